// Round 1
// baseline (1164.046 us; speedup 1.0000x reference)
//
#include <hip/hip_runtime.h>
#include <hip/hip_bf16.h>
#include <stdint.h>

// Problem constants (SNNExoplanetDetector): B=256 batch, T=1000 steps,
// F=128 input feats, H=256 hidden, O=2 outputs.
constexpr int B = 256, T = 1000, F = 128, H = 256, O = 2;
constexpr float DT_TAU_MEM = 0.1f;   // DT * TAU_MEM_INV
constexpr float SYN_DECAY  = 0.8f;   // 1 - DT * TAU_SYN_INV
constexpr float V_THRESH   = 1.0f;

// ---------------------------------------------------------------------------
// Storage-type adapters for xw (fp32 if workspace fits it, else bf16).
// ---------------------------------------------------------------------------
__device__ inline unsigned short f2bf_raw(float f) {
  __hip_bfloat16 b = __float2bfloat16(f);
  return *reinterpret_cast<unsigned short*>(&b);
}

template <typename XT> struct XConv;
template <> struct XConv<float> {
  static __device__ inline float load(const float* p) { return *p; }
  static __device__ inline void store4(float* p, float a, float b, float c, float d) {
    *reinterpret_cast<float4*>(p) = make_float4(a, b, c, d);
  }
};
template <> struct XConv<__hip_bfloat16> {
  static __device__ inline float load(const __hip_bfloat16* p) { return __bfloat162float(*p); }
  static __device__ inline void store4(__hip_bfloat16* p, float a, float b, float c, float d) {
    ushort4 u = make_ushort4(f2bf_raw(a), f2bf_raw(b), f2bf_raw(c), f2bf_raw(d));
    *reinterpret_cast<ushort4*>(p) = u;
  }
};

// ---------------------------------------------------------------------------
// Transpose w_rec [h][k] -> wT [k][h]  (so a spike k gathers a contiguous row)
// Tiny (256 KB); stays L2-resident for the scan kernel.
// ---------------------------------------------------------------------------
__global__ void transpose_wrec(const float* __restrict__ w, float* __restrict__ wT) {
  int k = blockIdx.x;
  int h = threadIdx.x;
  wT[k * H + h] = w[h * H + k];
}

// ---------------------------------------------------------------------------
// GEMM: xw[m][n] = sum_k x[m][k] * w_in[n][k];  M = B*T = 256000, K=128, N=256
// 64x64 block tile, 256 threads, 4x4 micro-tile, full K staged in LDS
// (transposed, padded stride 68 to dodge bank conflicts on the b128 reads).
// ---------------------------------------------------------------------------
template <typename XT>
__global__ __launch_bounds__(256) void gemm_xw(const float* __restrict__ x,
                                               const float* __restrict__ w_in,
                                               XT* __restrict__ xw) {
  constexpr int K = 128;
  constexpr int SA = 68;  // padded LDS row stride (floats), multiple of 4 for b128
  __shared__ float As[K][SA];
  __shared__ float Bs[K][SA];

  const int m0 = blockIdx.x * 64;
  const int n0 = blockIdx.y * 64;
  const int tid = threadIdx.x;

  // Cooperative load: 64 rows x 128 cols for both A (x) and B (w_in),
  // stored k-major into LDS.
  {
    const int r  = tid >> 2;   // 0..63  (row within tile)
    const int cq = tid & 3;    // 0..3   (float4 phase)
    const float* xa = x    + (size_t)(m0 + r) * K;
    const float* xb = w_in + (size_t)(n0 + r) * K;
#pragma unroll
    for (int j = 0; j < 8; ++j) {
      const int c = (cq + (j << 2)) << 2;  // 0..124, step covers all 128
      float4 av = *reinterpret_cast<const float4*>(xa + c);
      float4 bv = *reinterpret_cast<const float4*>(xb + c);
      As[c + 0][r] = av.x; As[c + 1][r] = av.y; As[c + 2][r] = av.z; As[c + 3][r] = av.w;
      Bs[c + 0][r] = bv.x; Bs[c + 1][r] = bv.y; Bs[c + 2][r] = bv.z; Bs[c + 3][r] = bv.w;
    }
  }
  __syncthreads();

  const int tn = (tid & 15) << 2;  // 0,4,...,60
  const int tm = (tid >> 4) << 2;  // 0,4,...,60
  float acc[4][4] = {};

#pragma unroll 16
  for (int k = 0; k < K; ++k) {
    float4 a = *reinterpret_cast<const float4*>(&As[k][tm]);
    float4 b = *reinterpret_cast<const float4*>(&Bs[k][tn]);
    acc[0][0] += a.x * b.x; acc[0][1] += a.x * b.y; acc[0][2] += a.x * b.z; acc[0][3] += a.x * b.w;
    acc[1][0] += a.y * b.x; acc[1][1] += a.y * b.y; acc[1][2] += a.y * b.z; acc[1][3] += a.y * b.w;
    acc[2][0] += a.z * b.x; acc[2][1] += a.z * b.y; acc[2][2] += a.z * b.z; acc[2][3] += a.z * b.w;
    acc[3][0] += a.w * b.x; acc[3][1] += a.w * b.y; acc[3][2] += a.w * b.z; acc[3][3] += a.w * b.w;
  }

#pragma unroll
  for (int im = 0; im < 4; ++im) {
    XT* p = xw + (size_t)(m0 + tm + im) * H + (n0 + tn);
    XConv<XT>::store4(p, acc[im][0], acc[im][1], acc[im][2], acc[im][3]);
  }
}

// ---------------------------------------------------------------------------
// LIF scan: one block per batch element, thread h owns neuron h's (v, i).
// Recurrent term gathers rows of wT (= columns of w_rec) for spiking neurons
// of the PREVIOUS step (reference uses carry z). Spike list double-buffered
// in LDS -> 2 __syncthreads per step. xw prefetched 2 steps ahead.
// ---------------------------------------------------------------------------
template <typename XT>
__global__ __launch_bounds__(256) void scan_lif(const XT* __restrict__ xw,
                                                const float* __restrict__ wT,
                                                const float* __restrict__ fc_w,
                                                const float* __restrict__ fc_b,
                                                float* __restrict__ out) {
  const int b = blockIdx.x;
  const int h = threadIdx.x;

  __shared__ int   spk[2][H];
  __shared__ int   cnt[2];
  __shared__ float red[8];

  if (h < 2) cnt[h] = 0;
  __syncthreads();

  float v = 0.f, cur = 0.f;   // membrane v, synaptic current i
  int spike_count = 0;

  const XT* xrow = xw + (size_t)b * T * H + h;
  float x0 = XConv<XT>::load(xrow);
  float x1 = XConv<XT>::load(xrow + H);

  for (int t = 0; t < T; ++t) {
    const int cb = t & 1, nb = cb ^ 1;
    const float xt = x0;
    x0 = x1;
    x1 = (t + 2 < T) ? XConv<XT>::load(xrow + (size_t)(t + 2) * H) : 0.f;

    // recurrent gather over previous step's spikes (4-way batched for MLP)
    float rec = 0.f;
    const int c = cnt[cb];
    int j = 0;
    for (; j + 4 <= c; j += 4) {
      const int k0 = spk[cb][j + 0], k1 = spk[cb][j + 1];
      const int k2 = spk[cb][j + 2], k3 = spk[cb][j + 3];
      const float w0 = wT[(k0 << 8) + h];
      const float w1 = wT[(k1 << 8) + h];
      const float w2 = wT[(k2 << 8) + h];
      const float w3 = wT[(k3 << 8) + h];
      rec += (w0 + w1) + (w2 + w3);
    }
    for (; j < c; ++j) rec += wT[(spk[cb][j] << 8) + h];

    // LIF update (matches reference op order; Sterbenz => identical spikes
    // for identical inputs)
    const float v_dec = v + DT_TAU_MEM * (cur - v);
    const int z = v_dec > V_THRESH;
    v = z ? 0.f : v_dec;
    cur = cur * SYN_DECAY + xt + rec;
    spike_count += z;

    __syncthreads();  // all reads of spk[cb]/cnt[cb] done; cnt[nb] zero is visible
    if (z) { int p = atomicAdd(&cnt[nb], 1); spk[nb][p] = h; }
    if (h == 0) cnt[cb] = 0;  // prepared for appends at t+1
    __syncthreads();          // new list + zero visible before next step
  }

  // Readout: out[b][o] = sum_h count[h] * fc_w[o][h] + fc_b[o]
  const float cf = (float)spike_count;
#pragma unroll
  for (int o = 0; o < O; ++o) {
    float p = cf * fc_w[o * H + h];
#pragma unroll
    for (int off = 32; off > 0; off >>= 1) p += __shfl_down(p, off, 64);
    if ((h & 63) == 0) red[o * 4 + (h >> 6)] = p;
    __syncthreads();
  }
  if (h < O) {
    out[b * O + h] = (red[h * 4 + 0] + red[h * 4 + 1] + red[h * 4 + 2] + red[h * 4 + 3]) + fc_b[h];
  }
}

// ---------------------------------------------------------------------------
extern "C" void kernel_launch(void* const* d_in, const int* in_sizes, int n_in,
                              void* d_out, int out_size, void* d_ws, size_t ws_size,
                              hipStream_t stream) {
  const float* x     = (const float*)d_in[0];
  const float* w_in  = (const float*)d_in[1];
  const float* w_rec = (const float*)d_in[2];
  const float* fc_w  = (const float*)d_in[3];
  const float* fc_b  = (const float*)d_in[4];
  float* out = (float*)d_out;

  // workspace layout: [wT fp32 256KB][xw (fp32 if it fits, else bf16)]
  float* wT = (float*)d_ws;
  const size_t wT_bytes = (size_t)H * H * sizeof(float);
  char* xw_base = (char*)d_ws + wT_bytes;
  const size_t xw_elems = (size_t)B * T * H;
  const bool use_f32 = ws_size >= wT_bytes + xw_elems * sizeof(float);

  transpose_wrec<<<H, H, 0, stream>>>(w_rec, wT);

  if (use_f32) {
    float* xw = (float*)xw_base;
    gemm_xw<float><<<dim3(B * T / 64, H / 64), 256, 0, stream>>>(x, w_in, xw);
    scan_lif<float><<<B, H, 0, stream>>>(xw, wT, fc_w, fc_b, out);
  } else {
    __hip_bfloat16* xw = (__hip_bfloat16*)xw_base;
    gemm_xw<__hip_bfloat16><<<dim3(B * T / 64, H / 64), 256, 0, stream>>>(x, w_in, xw);
    scan_lif<__hip_bfloat16><<<B, H, 0, stream>>>(xw, wT, fc_w, fc_b, out);
  }
}